// Round 2
// baseline (159.729 us; speedup 1.0000x reference)
//
#include <hip/hip_runtime.h>
#include <hip/hip_bf16.h>

// u[b,o,y,x] = sum_d dist(p,d) * t[b,d,o],  t = v@W^T + bias
// GEMM: out[col*9216 + p] = sum_d D[p,d] * T[d, col],  col = b*32+o
// D generated on the fly in registers (1 sub + 1 fma + 1 sqrt per element).

typedef __bf16 bf16x8 __attribute__((ext_vector_type(8)));
typedef float  f32x4  __attribute__((ext_vector_type(4)));

#define HW     96
#define NPTS   9216      // 96*96
#define CIN    32
#define COUT   32
#define NCOLS  256       // 8 batches * 32 cout
#define SCALE  (1.0f / 95.0f)
#define BK     64
#define LSTR   144       // LDS bytes per col row: 64 bf16 = 128B + 16B pad

// ---------------- Kernel 1: projection  T2[col][d] = bf16(v . W^T + b) ----
__global__ __launch_bounds__(256) void proj_kernel(
    const float* __restrict__ v, const float* __restrict__ W,
    const float* __restrict__ bias, __bf16* __restrict__ T2)
{
    __shared__ float Wl[COUT * CIN];
    __shared__ float bl[COUT];
    const int t = threadIdx.x;
    for (int i = t; i < COUT * CIN; i += 256) Wl[i] = W[i];
    if (t < COUT) bl[t] = bias[t];
    __syncthreads();

    const int b = blockIdx.y;
    const int d = blockIdx.x * 256 + t;
    const float* vb = v + (size_t)b * CIN * NPTS + d;

    float acc[COUT];
#pragma unroll
    for (int o = 0; o < COUT; ++o) acc[o] = bl[o];
#pragma unroll 4
    for (int c = 0; c < CIN; ++c) {
        const float vv = vb[(size_t)c * NPTS];
#pragma unroll
        for (int o = 0; o < COUT; ++o) acc[o] += vv * Wl[o * CIN + c];
    }
#pragma unroll
    for (int o = 0; o < COUT; ++o)
        T2[(size_t)(b * COUT + o) * NPTS + d] = (__bf16)acc[o];
}

// ---------------- Kernel 2: implicit-D GEMM ------------------------------
// grid (144, 2): 64 rows (p) x 128 cols per block, 4 waves x 16 rows each.
__global__ __launch_bounds__(256) void gemm_kernel(
    const __bf16* __restrict__ T2, float* __restrict__ out)
{
    __shared__ __align__(16) unsigned char lds[128 * LSTR];

    const int tid  = threadIdx.x;
    const int wid  = tid >> 6;
    const int lane = tid & 63;
    const int g    = lane >> 4;      // k-group 0..3 (8 k each)
    const int cl   = lane & 15;      // col within 16-wide tile / row for A
    const int p0   = blockIdx.x * 64 + wid * 16;
    const int prow = p0 + cl;        // this lane's A row (point index p)
    const int yp   = prow / 96;
    const int xp   = prow - yp * 96;
    const float ypf = (float)yp * SCALE;
    const float xpf = (float)xp * SCALE;
    const int colBase = blockIdx.y * 128;

    // staging: 4 chunks of 16B per thread; 8 threads cover one col's 128B
    const int c0 = tid >> 3;                 // col 0..31 (+32*i)
    const int kc = tid & 7;                  // 16B chunk within 64-k row
    const __bf16* gbase = T2 + (size_t)(colBase + c0) * NPTS + kc * 8;
    const int lbase = c0 * LSTR + kc * 16;

    f32x4 acc[8] = {};

    // prologue: stage k-tile 0
#pragma unroll
    for (int i = 0; i < 4; ++i) {
        bf16x8 v0 = *(const bf16x8*)(gbase + (size_t)i * 32 * NPTS);
        *(bf16x8*)(lds + lbase + i * 32 * LSTR) = v0;
    }
    __syncthreads();

    int yd = 0, xb = 0;   // coords of current 32-wide k-subtile (96 = 3*32)
    for (int kt = 0; kt < 144; ++kt) {
        bf16x8 st[4];
        const bool more = (kt < 143);
        if (more) {
            const __bf16* gp = gbase + (size_t)(kt + 1) * BK;
#pragma unroll
            for (int i = 0; i < 4; ++i)
                st[i] = *(const bf16x8*)(gp + (size_t)i * 32 * NPTS);
        }
#pragma unroll
        for (int h = 0; h < 2; ++h) {
            // ---- A fragment: dist(prow, d), d = kt*64 + h*32 + g*8 + j
            const float dy  = ypf - (float)yd * SCALE;
            const float dy2 = dy * dy;
            float dx = xpf - (float)(xb + g * 8) * SCALE;
            bf16x8 a;
#pragma unroll
            for (int j = 0; j < 8; ++j) {
                const float s2 = __builtin_fmaf(dx, dx, dy2);
                a[j] = (__bf16)__builtin_amdgcn_sqrtf(s2);
                dx -= SCALE;
            }
            // ---- 8 column tiles
#pragma unroll
            for (int ct = 0; ct < 8; ++ct) {
                const bf16x8 bfrag = *(const bf16x8*)(
                    lds + (ct * 16 + cl) * LSTR + h * 64 + g * 16);
                acc[ct] = __builtin_amdgcn_mfma_f32_16x16x32_bf16(
                    a, bfrag, acc[ct], 0, 0, 0);
            }
            xb += 32;
            if (xb == 96) { xb = 0; ++yd; }
        }
        __syncthreads();
        if (more) {
#pragma unroll
            for (int i = 0; i < 4; ++i)
                *(bf16x8*)(lds + lbase + i * 32 * LSTR) = st[i];
        }
        __syncthreads();
    }

    // epilogue: C/D layout col=lane&15, row=g*4+r -> 4 consecutive p
#pragma unroll
    for (int ct = 0; ct < 8; ++ct) {
        const int col = colBase + ct * 16 + cl;
        *(f32x4*)(out + (size_t)col * NPTS + p0 + g * 4) = acc[ct];
    }
}

extern "C" void kernel_launch(void* const* d_in, const int* in_sizes, int n_in,
                              void* d_out, int out_size, void* d_ws, size_t ws_size,
                              hipStream_t stream) {
    const float* v    = (const float*)d_in[0];  // (8,32,96,96)
    const float* W    = (const float*)d_in[1];  // (32,32)
    const float* bias = (const float*)d_in[2];  // (32,)
    float* out = (float*)d_out;                 // (8,32,96,96) f32
    __bf16* T2 = (__bf16*)d_ws;                 // 256 x 9216 bf16 = 4.5 MB

    proj_kernel<<<dim3(36, 8), 256, 0, stream>>>(v, W, bias, T2);
    gemm_kernel<<<dim3(144, 2), 256, 0, stream>>>(T2, out);
}

// Round 3
// 104.357 us; speedup vs baseline: 1.5306x; 1.5306x over previous
//
#include <hip/hip_runtime.h>
#include <hip/hip_bf16.h>

// u[b,o,y,x] = sum_d dist(p,d) * t[b,d,o],  t = v@W^T + bias
// GEMM: out[col*9216 + p] = sum_d D[p,d] * T[d, col],  col = b*32+o
// D generated on the fly in registers. K split 4 ways for occupancy;
// partials in d_ws + reduce kernel (atomic fallback if ws too small).

typedef __bf16 bf16x8 __attribute__((ext_vector_type(8)));
typedef float  f32x4  __attribute__((ext_vector_type(4)));

#define HW     96
#define NPTS   9216      // 96*96
#define CIN    32
#define COUT   32
#define NCOLS  256       // 8 batches * 32 cout
#define SCALE  (1.0f / 95.0f)
#define BK     64
#define LSTR   144       // LDS bytes per col row: 64 bf16 = 128B + 16B pad
#define SPLIT  4
#define KT_PER 36        // 144 k-tiles / SPLIT
#define OUTN   (NCOLS * NPTS)

// ---------------- Kernel 1: projection  T2[col][d] = bf16(v . W^T + b) ----
__global__ __launch_bounds__(256) void proj_kernel(
    const float* __restrict__ v, const float* __restrict__ W,
    const float* __restrict__ bias, __bf16* __restrict__ T2)
{
    __shared__ float Wl[COUT * CIN];
    __shared__ float bl[COUT];
    const int t = threadIdx.x;
    for (int i = t; i < COUT * CIN; i += 256) Wl[i] = W[i];
    if (t < COUT) bl[t] = bias[t];
    __syncthreads();

    const int b = blockIdx.y;
    const int d = blockIdx.x * 256 + t;
    const float* vb = v + (size_t)b * CIN * NPTS + d;

    float acc[COUT];
#pragma unroll
    for (int o = 0; o < COUT; ++o) acc[o] = bl[o];
#pragma unroll 4
    for (int c = 0; c < CIN; ++c) {
        const float vv = vb[(size_t)c * NPTS];
#pragma unroll
        for (int o = 0; o < COUT; ++o) acc[o] += vv * Wl[o * CIN + c];
    }
#pragma unroll
    for (int o = 0; o < COUT; ++o)
        T2[(size_t)(b * COUT + o) * NPTS + d] = (__bf16)acc[o];
}

// ---------------- Kernel 2: implicit-D GEMM, K-split ---------------------
// grid (144, 2, SPLIT): 64 rows x 128 cols x (K/SPLIT) per block,
// 4 waves x 16 rows each. Double-buffered LDS, one barrier per k-tile.
__global__ __launch_bounds__(256) void gemm_kernel(
    const __bf16* __restrict__ T2, float* __restrict__ dst, int usePartial)
{
    __shared__ __align__(16) unsigned char lds[2][128 * LSTR];

    const int tid  = threadIdx.x;
    const int wid  = tid >> 6;
    const int lane = tid & 63;
    const int g    = lane >> 4;      // k-group 0..3 (8 k each)
    const int cl   = lane & 15;      // col within 16-wide tile / row for A
    const int p0   = blockIdx.x * 64 + wid * 16;
    const int prow = p0 + cl;        // this lane's A row (point index p)
    const int yp   = prow / 96;
    const int xp   = prow - yp * 96;
    const float ypf = (float)yp * SCALE;
    const float xpf = (float)xp * SCALE;
    const int colBase = blockIdx.y * 128;
    const int kz   = blockIdx.z;
    const int koff = kz * (KT_PER * BK);   // 2304 * kz, divisible by 96

    // staging: 4 chunks of 16B per thread; 8 threads cover one col's 128B
    const int c0 = tid >> 3;                 // col 0..31 (+32*i)
    const int kc = tid & 7;                  // 16B chunk within 64-k row
    const __bf16* gbase = T2 + (size_t)(colBase + c0) * NPTS + koff + kc * 8;
    const int lbase = c0 * LSTR + kc * 16;

    f32x4 acc[8] = {};

    // prologue: stage local k-tile 0 into buf 0
#pragma unroll
    for (int i = 0; i < 4; ++i) {
        bf16x8 v0 = *(const bf16x8*)(gbase + (size_t)i * 32 * NPTS);
        *(bf16x8*)(lds[0] + lbase + i * 32 * LSTR) = v0;
    }
    __syncthreads();

    int cur = 0;
    int yd = kz * 24, xb = 0;  // coords of current 32-wide k-subtile
    for (int kt = 0; kt < KT_PER; ++kt) {
        bf16x8 st[4];
        const bool more = (kt < KT_PER - 1);
        if (more) {
            const __bf16* gp = gbase + (size_t)(kt + 1) * BK;
#pragma unroll
            for (int i = 0; i < 4; ++i)
                st[i] = *(const bf16x8*)(gp + (size_t)i * 32 * NPTS);
        }
#pragma unroll
        for (int h = 0; h < 2; ++h) {
            // ---- A fragment: dist(prow, d), d = koff + kt*64 + h*32 + g*8 + j
            const float dy  = ypf - (float)yd * SCALE;
            const float dy2 = dy * dy;
            float dx = xpf - (float)(xb + g * 8) * SCALE;
            bf16x8 a;
#pragma unroll
            for (int j = 0; j < 8; ++j) {
                const float s2 = __builtin_fmaf(dx, dx, dy2);
                a[j] = (__bf16)__builtin_amdgcn_sqrtf(s2);
                dx -= SCALE;
            }
            // ---- 8 column tiles
#pragma unroll
            for (int ct = 0; ct < 8; ++ct) {
                const bf16x8 bfrag = *(const bf16x8*)(
                    lds[cur] + (ct * 16 + cl) * LSTR + h * 64 + g * 16);
                acc[ct] = __builtin_amdgcn_mfma_f32_16x16x32_bf16(
                    a, bfrag, acc[ct], 0, 0, 0);
            }
            xb += 32;
            if (xb == 96) { xb = 0; ++yd; }
        }
        if (more) {
#pragma unroll
            for (int i = 0; i < 4; ++i)
                *(bf16x8*)(lds[cur ^ 1] + lbase + i * 32 * LSTR) = st[i];
        }
        __syncthreads();
        cur ^= 1;
    }

    // epilogue: C/D layout col=lane&15, row=g*4+r -> 4 consecutive p
    if (usePartial) {
        float* pb = dst + (size_t)kz * OUTN;
#pragma unroll
        for (int ct = 0; ct < 8; ++ct) {
            const int col = colBase + ct * 16 + cl;
            *(f32x4*)(pb + (size_t)col * NPTS + p0 + g * 4) = acc[ct];
        }
    } else {
#pragma unroll
        for (int ct = 0; ct < 8; ++ct) {
            const int col = colBase + ct * 16 + cl;
            float* o = dst + (size_t)col * NPTS + p0 + g * 4;
#pragma unroll
            for (int r = 0; r < 4; ++r) atomicAdd(o + r, acc[ct][r]);
        }
    }
}

// ---------------- Kernel 3: reduce SPLIT partials ------------------------
__global__ __launch_bounds__(256) void reduce_kernel(
    const float* __restrict__ part, float* __restrict__ out)
{
    const int i = (blockIdx.x * 256 + threadIdx.x) * 4;
    f32x4 a = *(const f32x4*)(part + i);
#pragma unroll
    for (int s = 1; s < SPLIT; ++s) {
        f32x4 b = *(const f32x4*)(part + (size_t)s * OUTN + i);
        a += b;
    }
    *(f32x4*)(out + i) = a;
}

extern "C" void kernel_launch(void* const* d_in, const int* in_sizes, int n_in,
                              void* d_out, int out_size, void* d_ws, size_t ws_size,
                              hipStream_t stream) {
    const float* v    = (const float*)d_in[0];  // (8,32,96,96)
    const float* W    = (const float*)d_in[1];  // (32,32)
    const float* bias = (const float*)d_in[2];  // (32,)
    float* out = (float*)d_out;                 // (8,32,96,96) f32
    __bf16* T2 = (__bf16*)d_ws;                 // 256 x 9216 bf16 = 4.5 MB

    const size_t t2_bytes = (size_t)NCOLS * NPTS * 2;          // 4.72 MB
    const size_t need = t2_bytes + (size_t)SPLIT * OUTN * 4;   // + 37.7 MB
    const int usePartial = (ws_size >= need) ? 1 : 0;
    float* partial = (float*)((char*)d_ws + t2_bytes);

    proj_kernel<<<dim3(36, 8), 256, 0, stream>>>(v, W, bias, T2);
    if (!usePartial)
        hipMemsetAsync(d_out, 0, (size_t)out_size * sizeof(float), stream);
    gemm_kernel<<<dim3(144, 2, SPLIT), 256, 0, stream>>>(
        T2, usePartial ? partial : out, usePartial);
    if (usePartial)
        reduce_kernel<<<OUTN / 1024, 256, 0, stream>>>(partial, out);
}